// Round 3
// baseline (1484.146 us; speedup 1.0000x reference)
//
#include <hip/hip_runtime.h>
#include <hip/hip_bf16.h>
#include <hip/hip_fp8.h>

// MatchingLayer: B=8, S=2048, H=1024
//   scores = (X X^T)/32 -> mask -> softmax -> context = P X
//   matching = [X|context] @ W + b -> LayerNorm
// All GEMMs: 256x256 tile, quad-buffered LDS, counted-vmcnt pipeline with
// REGISTER-DOUBLE-BUFFERED fragments: iter T = {vmcnt(N); s_barrier;
// STAGE(T+3); ds_read frags(T+1) -> other reg set; MFMA(T)}. The MFMA burst
// hides ds_read issue+latency (m196's fine-interleave lever). vmcnt never 0
// until tail. T2 XOR swizzle pre-applied on global source (rule #21).
// gemm1 fp8: BK=32 (b64 frags, full reg-dbuf); gemm_bt bf16: BK=32
// (af reg-dbuf, bf reloaded after MFMA).
// WORKSPACE REQUIREMENT: 172,032,000 bytes (X8 aliases CTX region).

typedef unsigned short ushort_t;
typedef __attribute__((ext_vector_type(8))) short short8;
typedef __attribute__((ext_vector_type(4))) float float4v;

__device__ inline float b2f(unsigned int u) {
    union { unsigned int i; float f; } v; v.i = u << 16; return v.f;
}
__device__ inline ushort_t f2b(float f) {
    __hip_bfloat16 h = __float2bfloat16(f);
    return __builtin_bit_cast(ushort_t, h);
}
__device__ inline unsigned char f2e4(float f) {
    return __hip_fp8_e4m3(f).__x;
}

// async global->LDS DMA, 16B per lane; lds base wave-uniform, lane i -> lds+i*16.
__device__ inline void gload_lds16(const void* g, void* lds) {
    __builtin_amdgcn_global_load_lds(
        (const __attribute__((address_space(1))) unsigned int*)g,
        (__attribute__((address_space(3))) unsigned int*)lds, 16, 0, 0);
}

// ---------------- bf16 GEMM:  C[m][n] = sum_k A[m][k]*B[n][k] ----------------
// 256x256 tile, BK=32, 4 LDS buffers (128 KiB), 512 thr = 8 waves (2Mx4N),
// per-wave C = 128x64 = 8x4 frags. Register pipeline: af double-buffered
// (afA/afB), bf single-set reloaded after the MFMA burst.
// A dual-sourced at kSplit (for [X|ctx] concat).
// EPI 2: v / rowsum[row] -> bf16    EPI 3: v + bias[col] -> bf16
template<int EPI>
__global__ __launch_bounds__(512, 2)
void gemm_bt(const ushort_t* __restrict__ A, const ushort_t* __restrict__ A2, int kSplit,
             const ushort_t* __restrict__ B,
             int M, int N, int K, int lda, int ldb, int ldc,
             long aBS, long bBS, long cBS,
             const float* __restrict__ rowsum,
             const float* __restrict__ bias,
             ushort_t* __restrict__ outb)
{
    __shared__ __align__(16) ushort_t smem[4 * 16384];  // 4 x (A 16KB + B 16KB)

    const int tid = threadIdx.x;
    const int z = blockIdx.z;
    A  += (size_t)z * aBS;
    A2 += (size_t)z * aBS;
    B  += (size_t)z * bBS;
    if (EPI == 2) rowsum += (size_t)z * M;
    outb += (size_t)z * cBS;

    const int bm = blockIdx.x * 256;
    const int bn = blockIdx.y * 256;
    const int w = tid >> 6, lane = tid & 63;
    const int wm = (w >> 2) * 128, wn = (w & 3) * 64;
    const int q = lane >> 4, l15 = lane & 15;
    const int srow = lane >> 2;                               // 16 rows / staging pass
    const int schunk = ((lane & 3) ^ ((lane >> 3) & 3)) * 8;  // pre-swizzled src chunk (elems)

    float4v acc[8][4];
#pragma unroll
    for (int i = 0; i < 8; i++)
#pragma unroll
        for (int j = 0; j < 4; j++) acc[i][j] = (float4v){0.f, 0.f, 0.f, 0.f};

    const int NT = K >> 5;   // K-tiles of 32

#define STAGE(T) do {                                                               \
        const int k0_ = (T) * 32;                                                   \
        const ushort_t* aS_ = A; int ka_ = k0_;                                     \
        if (k0_ >= kSplit) { aS_ = A2; ka_ = k0_ - kSplit; }                        \
        ushort_t* buf_ = &smem[((T) & 3) * 16384];                                  \
        gload_lds16(aS_ + (size_t)(bm + w * 16       + srow) * lda + ka_ + schunk,  \
                    buf_ + w * 512);                                                \
        gload_lds16(aS_ + (size_t)(bm + (w + 8) * 16 + srow) * lda + ka_ + schunk,  \
                    buf_ + (w + 8) * 512);                                          \
        gload_lds16(B   + (size_t)(bn + w * 16       + srow) * ldb + k0_ + schunk,  \
                    buf_ + 8192 + w * 512);                                         \
        gload_lds16(B   + (size_t)(bn + (w + 8) * 16 + srow) * ldb + k0_ + schunk,  \
                    buf_ + 8192 + (w + 8) * 512);                                   \
    } while (0)

#define LOAD_AF(dst, bufA_) do {                                                    \
        _Pragma("unroll")                                                           \
        for (int mi_ = 0; mi_ < 8; mi_++) {                                         \
            const int r_ = wm + mi_ * 16 + l15;                                     \
            dst[mi_] = *(const short8*)(&(bufA_)[r_ * 32 + ((q ^ ((r_ >> 1) & 3)) << 3)]); \
        } } while (0)

#define LOAD_BF(dst, bufB_) do {                                                    \
        _Pragma("unroll")                                                           \
        for (int ni_ = 0; ni_ < 4; ni_++) {                                         \
            const int r_ = wn + ni_ * 16 + l15;                                     \
            dst[ni_] = *(const short8*)(&(bufB_)[r_ * 32 + ((q ^ ((r_ >> 1) & 3)) << 3)]); \
        } } while (0)

#define MFMA_BT(afx) do {                                                           \
        __builtin_amdgcn_s_setprio(1);                                              \
        _Pragma("unroll")                                                           \
        for (int mi_ = 0; mi_ < 8; mi_++)                                           \
            _Pragma("unroll")                                                       \
            for (int ni_ = 0; ni_ < 4; ni_++)                                       \
                acc[mi_][ni_] = __builtin_amdgcn_mfma_f32_16x16x32_bf16(            \
                    afx[mi_], bfS[ni_], acc[mi_][ni_], 0, 0, 0);                    \
        __builtin_amdgcn_s_setprio(0); } while (0)

    short8 afA[8], afB[8], bfS[4];

    // prologue: 3-deep prefetch, land tile 0, preload its fragments
    STAGE(0); STAGE(1); STAGE(2);
    asm volatile("s_waitcnt vmcnt(8)\n\ts_barrier" ::: "memory");
    LOAD_AF(afA, (&smem[0]));
    LOAD_BF(bfS, (&smem[8192]));

    for (int T = 0; T < NT; T += 2) {
        {   // even tile: compute afA, prefetch tile T+1 into afB
            if (T + 2 < NT) asm volatile("s_waitcnt vmcnt(4)\n\ts_barrier" ::: "memory");
            else            asm volatile("s_waitcnt vmcnt(0)\n\ts_barrier" ::: "memory");
            if (T + 3 < NT) STAGE(T + 3);
            const ushort_t* nb = &smem[((T + 1) & 3) * 16384];
            LOAD_AF(afB, nb);
            MFMA_BT(afA);
            LOAD_BF(bfS, (nb + 8192));
        }
        {   // odd tile U=T+1
            const int U = T + 1;
            if (U + 1 < NT) {
                if (U + 2 < NT) asm volatile("s_waitcnt vmcnt(4)\n\ts_barrier" ::: "memory");
                else            asm volatile("s_waitcnt vmcnt(0)\n\ts_barrier" ::: "memory");
                if (U + 3 < NT) STAGE(U + 3);
                const ushort_t* nb = &smem[((U + 1) & 3) * 16384];
                LOAD_AF(afA, nb);
                MFMA_BT(afB);
                LOAD_BF(bfS, (nb + 8192));
            } else {
                MFMA_BT(afB);
            }
        }
    }
#undef STAGE
#undef LOAD_AF
#undef LOAD_BF
#undef MFMA_BT

    // D layout (m89): col = lane&15, row = (lane>>4)*4 + reg
#pragma unroll
    for (int mi = 0; mi < 8; mi++) {
#pragma unroll
        for (int r = 0; r < 4; r++) {
            const int row = bm + wm + mi * 16 + q * 4 + r;
            const size_t ro = (size_t)row * ldc;
            float rsinv = 1.f;
            if (EPI == 2) rsinv = 1.0f / rowsum[row];
#pragma unroll
            for (int ni = 0; ni < 4; ni++) {
                const int col = bn + wn + ni * 16 + l15;
                float v = acc[mi][ni][r];
                if (EPI == 2) outb[ro + col] = f2b(v * rsinv);
                else          outb[ro + col] = f2b(v + bias[col]);
            }
        }
    }
}

// ---------------- fp8 GEMM1: E = exp(mask(scale * X X^T)), rowsum ----------------
// 256x256 tile, BK=32 (32 B/row fp8), 4 LDS buffers (64 KiB), 512 thr = 8 waves.
// Full register double-buffer of fragments (b64 frags, 2 VGPR each).
// Swizzle for 32B rows: 8B granule g -> g ^ (((row>>2)&1)<<1)  (even XOR keeps
// 16B source chunks contiguous; 2-way bank aliasing only = free per m136).
__global__ __launch_bounds__(512, 2)
void gemm1_fp8(const unsigned char* __restrict__ X8,
               const float* __restrict__ mask,
               float* __restrict__ rowsum,
               ushort_t* __restrict__ E)
{
    __shared__ __align__(16) unsigned char smem[4 * 16384];  // 4 x (A 8KB + B 8KB)

    const int tid = threadIdx.x;
    const int z = blockIdx.z;
    const unsigned char* Xz = X8 + (size_t)z * 2048 * 1024;
    const float* mz = mask + (size_t)z * 2048 * 2048;
    float* rsz = rowsum + (size_t)z * 2048;
    ushort_t* Ez = E + (size_t)z * 2048 * 2048;

    const int bm = blockIdx.x * 256;
    const int bn = blockIdx.y * 256;
    const int w = tid >> 6, lane = tid & 63;
    const int wm = (w >> 2) * 128, wn = (w & 3) * 64;
    const int q = lane >> 4, l15 = lane & 15;
    const int srow = lane >> 1;                               // 32 rows / staging pass
    const int sch = ((lane & 1) ^ ((lane >> 3) & 1)) * 16;    // pre-swizzled src chunk (bytes)

    float4v acc[8][4];
#pragma unroll
    for (int i = 0; i < 8; i++)
#pragma unroll
        for (int j = 0; j < 4; j++) acc[i][j] = (float4v){0.f, 0.f, 0.f, 0.f};

    // K=1024 -> 32 K-tiles of 32
#define STAGE1(T) do {                                                              \
        const int k0_ = (T) * 32;                                                   \
        unsigned char* buf_ = &smem[((T) & 3) * 16384];                             \
        gload_lds16(Xz + (size_t)(bm + w * 32 + srow) * 1024 + k0_ + sch,           \
                    buf_ + w * 1024);                                               \
        gload_lds16(Xz + (size_t)(bn + w * 32 + srow) * 1024 + k0_ + sch,           \
                    buf_ + 8192 + w * 1024);                                        \
    } while (0)

#define LOAD1(afx, bfx, buf_) do {                                                  \
        _Pragma("unroll")                                                           \
        for (int mi_ = 0; mi_ < 8; mi_++) {                                         \
            const int r_ = wm + mi_ * 16 + l15;                                     \
            afx[mi_] = *(const long*)(&(buf_)[r_ * 32 + ((q ^ (((r_ >> 2) & 1) << 1)) << 3)]); \
        }                                                                           \
        _Pragma("unroll")                                                           \
        for (int ni_ = 0; ni_ < 4; ni_++) {                                         \
            const int r_ = wn + ni_ * 16 + l15;                                     \
            bfx[ni_] = *(const long*)(&(buf_)[8192 + r_ * 32 + ((q ^ (((r_ >> 2) & 1) << 1)) << 3)]); \
        } } while (0)

#define MFMA1(afx, bfx) do {                                                        \
        __builtin_amdgcn_s_setprio(1);                                              \
        _Pragma("unroll")                                                           \
        for (int mi_ = 0; mi_ < 8; mi_++)                                           \
            _Pragma("unroll")                                                       \
            for (int ni_ = 0; ni_ < 4; ni_++)                                       \
                acc[mi_][ni_] = __builtin_amdgcn_mfma_f32_16x16x32_fp8_fp8(         \
                    afx[mi_], bfx[ni_], acc[mi_][ni_], 0, 0, 0);                    \
        __builtin_amdgcn_s_setprio(0); } while (0)

    long afA[8], bfA[4], afB[8], bfB[4];

    STAGE1(0); STAGE1(1); STAGE1(2);
    asm volatile("s_waitcnt vmcnt(4)\n\ts_barrier" ::: "memory");
    LOAD1(afA, bfA, (&smem[0]));

    for (int T = 0; T < 32; T += 2) {
        {   // even tile: compute (afA,bfA), prefetch T+1 into (afB,bfB)
            if (T + 2 < 32) asm volatile("s_waitcnt vmcnt(2)\n\ts_barrier" ::: "memory");
            else            asm volatile("s_waitcnt vmcnt(0)\n\ts_barrier" ::: "memory");
            if (T + 3 < 32) STAGE1(T + 3);
            LOAD1(afB, bfB, (&smem[((T + 1) & 3) * 16384]));
            MFMA1(afA, bfA);
        }
        {   // odd tile U=T+1
            const int U = T + 1;
            if (U + 1 < 32) {
                if (U + 2 < 32) asm volatile("s_waitcnt vmcnt(2)\n\ts_barrier" ::: "memory");
                else            asm volatile("s_waitcnt vmcnt(0)\n\ts_barrier" ::: "memory");
                if (U + 3 < 32) STAGE1(U + 3);
                LOAD1(afA, bfA, (&smem[((U + 1) & 3) * 16384]));
                MFMA1(afB, bfB);
            } else {
                MFMA1(afB, bfB);
            }
        }
    }
#undef STAGE1
#undef LOAD1
#undef MFMA1

    const float scale = 0.03125f;  // 1/sqrt(1024)
#pragma unroll
    for (int mi = 0; mi < 8; mi++) {
#pragma unroll
        for (int r = 0; r < 4; r++) {
            const int row = bm + wm + mi * 16 + q * 4 + r;
            const size_t ro = (size_t)row * 2048;
            float s = 0.f;
#pragma unroll
            for (int ni = 0; ni < 4; ni++) {
                const int col = bn + wn + ni * 16 + l15;
                const float m = mz[ro + col];
                float v = __expf(acc[mi][ni][r] * scale * m - 1e9f * (1.0f - m));
                s += v;
                Ez[ro + col] = f2b(v);
            }
            s += __shfl_xor(s, 8);
            s += __shfl_xor(s, 4);
            s += __shfl_xor(s, 2);
            s += __shfl_xor(s, 1);
            if (l15 == 0) atomicAdd(&rsz[row], s);
        }
    }
}

// fp32 [R][C] (batched z) -> outT bf16 [C][R]; optional outS bf16 + outQ fp8 [R][C].
__global__ __launch_bounds__(256)
void conv_trans(const float* __restrict__ in, ushort_t* __restrict__ outT,
                ushort_t* __restrict__ outS, unsigned char* __restrict__ outQ,
                int R, int C)
{
    __shared__ float tile[64][65];
    const int tx = threadIdx.x & 15, ty = threadIdx.x >> 4;
    const size_t zoff = (size_t)blockIdx.z * R * C;
    const int r0 = blockIdx.y * 64, c0 = blockIdx.x * 64;
#pragma unroll
    for (int j = 0; j < 4; j++) {
        const int r = ty + j * 16;
        const float4 v = *(const float4*)(in + zoff + (size_t)(r0 + r) * C + c0 + tx * 4);
        tile[r][tx * 4 + 0] = v.x;
        tile[r][tx * 4 + 1] = v.y;
        tile[r][tx * 4 + 2] = v.z;
        tile[r][tx * 4 + 3] = v.w;
        if (outS) {
            ushort4 o;
            o.x = f2b(v.x); o.y = f2b(v.y); o.z = f2b(v.z); o.w = f2b(v.w);
            *(ushort4*)(outS + zoff + (size_t)(r0 + r) * C + c0 + tx * 4) = o;
            uchar4 p;
            p.x = f2e4(v.x); p.y = f2e4(v.y); p.z = f2e4(v.z); p.w = f2e4(v.w);
            *(uchar4*)(outQ + zoff + (size_t)(r0 + r) * C + c0 + tx * 4) = p;
        }
    }
    __syncthreads();
    ushort_t* tp = outT + zoff;
#pragma unroll
    for (int j = 0; j < 4; j++) {
        const int cc = ty + j * 16;
        ushort4 o;
        o.x = f2b(tile[tx * 4 + 0][cc]);
        o.y = f2b(tile[tx * 4 + 1][cc]);
        o.z = f2b(tile[tx * 4 + 2][cc]);
        o.w = f2b(tile[tx * 4 + 3][cc]);
        *(ushort4*)(tp + (size_t)(c0 + cc) * R + r0 + tx * 4) = o;
    }
}

// LayerNorm over H=1024 (bf16 in, fp32 out), one block (256 thr) per row.
__global__ __launch_bounds__(256)
void ln_k(const ushort_t* __restrict__ Mt, const float* __restrict__ gamma,
          const float* __restrict__ beta, float* __restrict__ out)
{
    const size_t row = blockIdx.x;
    const int tid = threadIdx.x;
    const ushort4 u = *(const ushort4*)(Mt + row * 1024 + tid * 4);
    float x0 = b2f(u.x), x1 = b2f(u.y), x2 = b2f(u.z), x3 = b2f(u.w);
    float s  = x0 + x1 + x2 + x3;
    float s2 = x0 * x0 + x1 * x1 + x2 * x2 + x3 * x3;
#pragma unroll
    for (int off = 32; off > 0; off >>= 1) {
        s  += __shfl_down(s, off);
        s2 += __shfl_down(s2, off);
    }
    __shared__ float red[8];
    const int wave = tid >> 6, lane = tid & 63;
    if (lane == 0) { red[wave] = s; red[4 + wave] = s2; }
    __syncthreads();
    s  = red[0] + red[1] + red[2] + red[3];
    s2 = red[4] + red[5] + red[6] + red[7];
    const float mu  = s * (1.0f / 1024.0f);
    const float var = s2 * (1.0f / 1024.0f) - mu * mu;
    const float rinv = rsqrtf(var + 1e-12f);
    const float4 g = *(const float4*)(gamma + tid * 4);
    const float4 b = *(const float4*)(beta + tid * 4);
    float4 o;
    o.x = (x0 - mu) * rinv * g.x + b.x;
    o.y = (x1 - mu) * rinv * g.y + b.y;
    o.z = (x2 - mu) * rinv * g.z + b.z;
    o.w = (x3 - mu) * rinv * g.w + b.w;
    *(float4*)(out + row * 1024 + tid * 4) = o;
}

extern "C" void kernel_launch(void* const* d_in, const int* in_sizes, int n_in,
                              void* d_out, int out_size, void* d_ws, size_t ws_size,
                              hipStream_t stream)
{
    const float* X     = (const float*)d_in[0];  // [8,2048,1024]
    const float* masks = (const float*)d_in[1];  // [8,2048,2048]
    const float* Wm    = (const float*)d_in[2];  // [2048,1024]
    const float* bias  = (const float*)d_in[3];  // [1024]
    const float* gamma = (const float*)d_in[4];  // [1024]
    const float* beta  = (const float*)d_in[5];  // [1024]
    float* out = (float*)d_out;
    char* ws = (char*)d_ws;

    const int B = 8, S = 2048, H = 1024;

    // workspace layout (bytes): total 172,032,000
    ushort_t* Xb  = (ushort_t*)(ws);              // 33,554,432  X bf16 [B][S][H]
    ushort_t* XT  = (ushort_t*)(ws + 33554432);   // 33,554,432  X^T bf16 [B][H][S]
    ushort_t* WT  = (ushort_t*)(ws + 67108864);   //  4,194,304  W^T bf16 [H][2H]
    ushort_t* E   = (ushort_t*)(ws + 71303168);   // 67,108,864  exp(logits) bf16 [B][S][S]
    float*    rs  = (float*)   (ws + 138412032);  //     65,536  rowsums [B][S]
    ushort_t* CTX = (ushort_t*)(ws + 138477568);  // 33,554,432  context bf16 [B][S][H]
    unsigned char* X8 = (unsigned char*)CTX;      // alias: X8 dead before CTX written
    ushort_t* matching = E;                       // alias: E dead after GEMM2

    conv_trans<<<dim3(16, 32, 8), 256, 0, stream>>>(X, XT, Xb, X8, S, H);
    conv_trans<<<dim3(16, 32, 1), 256, 0, stream>>>(Wm, WT, nullptr, nullptr, 2 * H, H);
    hipMemsetAsync(rs, 0, (size_t)B * S * sizeof(float), stream);

    // GEMM1 (fp8, reg-pipelined): E = exp(mask(scale * X X^T)); rs += row sums
    gemm1_fp8<<<dim3(8, 8, 8), 512, 0, stream>>>(X8, masks, rs, E);

    // GEMM2 (bf16, reg-pipelined): CTX = (E . XT^T) / rowsum
    gemm_bt<2><<<dim3(8, 4, 8), 512, 0, stream>>>(
        E, E, 1 << 30, XT,
        S, H, S, S, S, H,
        (long)S * S, (long)H * S, (long)S * H,
        rs, nullptr, CTX);

    // GEMM3 (bf16, reg-pipelined): matching = [Xb|CTX] @ WT^T + bias -> bf16
    gemm_bt<3><<<dim3(64, 4, 1), 512, 0, stream>>>(
        Xb, CTX, H, WT,
        B * S, H, 2 * H, H, 2 * H, H,
        0, 0, 0,
        nullptr, bias, matching);

    ln_k<<<B * S, 256, 0, stream>>>(matching, gamma, beta, out);
}

// Round 4
// 497.444 us; speedup vs baseline: 2.9835x; 2.9835x over previous
//
#include <hip/hip_runtime.h>
#include <hip/hip_bf16.h>
#include <hip/hip_fp8.h>

// MatchingLayer: B=8, S=2048, H=1024
//   scores = (X X^T)/32 -> mask -> softmax -> context = P X
//   matching = [X|context] @ W + b -> LayerNorm
// GEMMs use the m201-style fine-phase schedule on a 4-buffer LDS rotation:
//   per phase: {ds_read quadrant; issue stage loads; s_barrier; setprio(1);
//               16 MFMA; setprio(0); s_barrier}
//   counted s_waitcnt vmcnt(8) once per K-step (3 K-steps of loads in flight,
//   never drained to 0 until the tail).
// gemm_bt bf16: BK=32 (64B rows), 2 phases/K-step. gemm1 fp8: BK=64 (64B rows),
// 4 phases/K-step, 2 MFMA k-steps per ds_read_b128 (granule pairing, verified).
// T2 XOR swizzle pre-applied on the global source (rule #21), read-side XOR
// (q ^ ((row>>1)&3)) -> 2-way bank aliasing only (free, m136).
// WORKSPACE REQUIREMENT: 172,032,000 bytes (X8 aliases CTX region).

typedef unsigned short ushort_t;
typedef __attribute__((ext_vector_type(8))) short short8;
typedef __attribute__((ext_vector_type(4))) float float4v;
typedef __attribute__((ext_vector_type(2))) long long2v;

__device__ inline float b2f(unsigned int u) {
    union { unsigned int i; float f; } v; v.i = u << 16; return v.f;
}
__device__ inline ushort_t f2b(float f) {
    __hip_bfloat16 h = __float2bfloat16(f);
    return __builtin_bit_cast(ushort_t, h);
}
__device__ inline unsigned char f2e4(float f) {
    return __hip_fp8_e4m3(f).__x;
}

// async global->LDS DMA, 16B per lane; lds base wave-uniform, lane i -> lds+i*16.
__device__ inline void gload_lds16(const void* g, void* lds) {
    __builtin_amdgcn_global_load_lds(
        (const __attribute__((address_space(1))) unsigned int*)g,
        (__attribute__((address_space(3))) unsigned int*)lds, 16, 0, 0);
}

// ---------------- bf16 GEMM:  C[m][n] = sum_k A[m][k]*B[n][k] ----------------
// 256x256 tile, BK=32, 4 LDS buffers x (A 16KB + B 16KB) = 128 KiB,
// 512 thr = 8 waves (2Mx4N), per-wave C = 128x64 = 8x4 frags.
// Per K-step: 2 phases x 16 MFMA. Stage A-halves in phase a, B-halves in
// phase b, 3 K-steps ahead into buf (t+3)&3 (free since K-step t-1).
// A dual-sourced at kSplit (for [X|ctx] concat).
// EPI 2: v / rowsum[row] -> bf16    EPI 3: v + bias[col] -> bf16
template<int EPI>
__global__ __launch_bounds__(512, 2)
void gemm_bt(const ushort_t* __restrict__ A, const ushort_t* __restrict__ A2, int kSplit,
             const ushort_t* __restrict__ B,
             int M, int N, int K, int lda, int ldb, int ldc,
             long aBS, long bBS, long cBS,
             const float* __restrict__ rowsum,
             const float* __restrict__ bias,
             ushort_t* __restrict__ outb)
{
    __shared__ __align__(16) ushort_t smem[4 * 16384];

    const int tid = threadIdx.x;
    const int z = blockIdx.z;
    A  += (size_t)z * aBS;
    A2 += (size_t)z * aBS;
    B  += (size_t)z * bBS;
    if (EPI == 2) rowsum += (size_t)z * M;
    outb += (size_t)z * cBS;

    const int bm = blockIdx.x * 256;
    const int bn = blockIdx.y * 256;
    const int w = tid >> 6, lane = tid & 63;
    const int wm = (w >> 2) * 128, wn = (w & 3) * 64;
    const int q = lane >> 4, l15 = lane & 15;
    const int srow = lane >> 2;                               // 16 rows / gload
    const int schunk = ((lane & 3) ^ ((lane >> 3) & 3)) * 8;  // pre-swizzled src chunk (elems)

    float4v acc[8][4];
#pragma unroll
    for (int i = 0; i < 8; i++)
#pragma unroll
        for (int j = 0; j < 4; j++) acc[i][j] = (float4v){0.f, 0.f, 0.f, 0.f};

    const int NT = K >> 5;   // K-steps of 32

    auto stageA = [&](int T) {
        const int k0 = T * 32;
        const ushort_t* aS = A; int ka = k0;
        if (k0 >= kSplit) { aS = A2; ka = k0 - kSplit; }
        ushort_t* buf = &smem[(T & 3) * 16384];
        gload_lds16(aS + (size_t)(bm + w * 16       + srow) * lda + ka + schunk, buf + w * 512);
        gload_lds16(aS + (size_t)(bm + (w + 8) * 16 + srow) * lda + ka + schunk, buf + (w + 8) * 512);
    };
    auto stageB = [&](int T) {
        const int k0 = T * 32;
        ushort_t* buf = &smem[(T & 3) * 16384] + 8192;
        gload_lds16(B + (size_t)(bn + w * 16       + srow) * ldb + k0 + schunk, buf + w * 512);
        gload_lds16(B + (size_t)(bn + (w + 8) * 16 + srow) * ldb + k0 + schunk, buf + (w + 8) * 512);
    };

    // prologue: 3 K-steps in flight, land step 0
    stageA(0); stageB(0); stageA(1); stageB(1); stageA(2); stageB(2);
    asm volatile("s_waitcnt vmcnt(8)" ::: "memory");
    __builtin_amdgcn_s_barrier();

    short8 af[4], bf[4];
    for (int t = 0; t < NT; ++t) {
        const ushort_t* bufA = &smem[(t & 3) * 16384];
        const ushort_t* bufB = bufA + 8192;

        // ---- phase a: mi 0-3 x ni 0-3 ----
#pragma unroll
        for (int mi = 0; mi < 4; mi++) {
            const int r = wm + mi * 16 + l15;
            af[mi] = *(const short8*)(&bufA[r * 32 + ((q ^ ((r >> 1) & 3)) << 3)]);
        }
#pragma unroll
        for (int ni = 0; ni < 4; ni++) {
            const int r = wn + ni * 16 + l15;
            bf[ni] = *(const short8*)(&bufB[r * 32 + ((q ^ ((r >> 1) & 3)) << 3)]);
        }
        if (t + 3 < NT) stageA(t + 3);
        __builtin_amdgcn_s_barrier();
        __builtin_amdgcn_s_setprio(1);
#pragma unroll
        for (int mi = 0; mi < 4; mi++)
#pragma unroll
            for (int ni = 0; ni < 4; ni++)
                acc[mi][ni] = __builtin_amdgcn_mfma_f32_16x16x32_bf16(
                    af[mi], bf[ni], acc[mi][ni], 0, 0, 0);
        __builtin_amdgcn_s_setprio(0);
        __builtin_amdgcn_s_barrier();

        // ---- phase b: mi 4-7 x ni 0-3 ----
#pragma unroll
        for (int mi = 0; mi < 4; mi++) {
            const int r = wm + 64 + mi * 16 + l15;
            af[mi] = *(const short8*)(&bufA[r * 32 + ((q ^ ((r >> 1) & 3)) << 3)]);
        }
        if (t + 3 < NT) stageB(t + 3);
        __builtin_amdgcn_s_barrier();
        __builtin_amdgcn_s_setprio(1);
#pragma unroll
        for (int mi = 0; mi < 4; mi++)
#pragma unroll
            for (int ni = 0; ni < 4; ni++)
                acc[4 + mi][ni] = __builtin_amdgcn_mfma_f32_16x16x32_bf16(
                    af[mi], bf[ni], acc[4 + mi][ni], 0, 0, 0);
        __builtin_amdgcn_s_setprio(0);
        // counted drain: keep later K-steps' loads in flight; ensure t+1 landed
        if (t + 3 < NT)      asm volatile("s_waitcnt vmcnt(8)" ::: "memory");
        else if (t + 2 < NT) asm volatile("s_waitcnt vmcnt(4)" ::: "memory");
        else if (t + 1 < NT) asm volatile("s_waitcnt vmcnt(0)" ::: "memory");
        __builtin_amdgcn_s_barrier();
    }

    // D layout (m89): col = lane&15, row = (lane>>4)*4 + reg
#pragma unroll
    for (int mi = 0; mi < 8; mi++) {
#pragma unroll
        for (int r = 0; r < 4; r++) {
            const int row = bm + wm + mi * 16 + q * 4 + r;
            const size_t ro = (size_t)row * ldc;
            float rsinv = 1.f;
            if (EPI == 2) rsinv = 1.0f / rowsum[row];
#pragma unroll
            for (int ni = 0; ni < 4; ni++) {
                const int col = bn + wn + ni * 16 + l15;
                float v = acc[mi][ni][r];
                if (EPI == 2) outb[ro + col] = f2b(v * rsinv);
                else          outb[ro + col] = f2b(v + bias[col]);
            }
        }
    }
}

// ---------------- fp8 GEMM1: E = exp(mask(scale * X X^T)), rowsum ----------------
// 256x256 tile, BK=64 (64 B/row fp8), 4 LDS buffers x (A 16KB + B 16KB) = 128 KiB.
// Per K-step: 4 phases x 16 MFMA (quadrants (miHalf,niHalf)); each ds_read_b128
// feeds 2 fp8 MFMA k-steps (granule pairing, round-2-verified). NT=16.
__global__ __launch_bounds__(512, 2)
void gemm1_fp8(const unsigned char* __restrict__ X8,
               const float* __restrict__ mask,
               float* __restrict__ rowsum,
               ushort_t* __restrict__ E)
{
    __shared__ __align__(16) unsigned char smem[4 * 32768];

    const int tid = threadIdx.x;
    const int z = blockIdx.z;
    const unsigned char* Xz = X8 + (size_t)z * 2048 * 1024;
    const float* mz = mask + (size_t)z * 2048 * 2048;
    float* rsz = rowsum + (size_t)z * 2048;
    ushort_t* Ez = E + (size_t)z * 2048 * 2048;

    const int bm = blockIdx.x * 256;
    const int bn = blockIdx.y * 256;
    const int w = tid >> 6, lane = tid & 63;
    const int wm = (w >> 2) * 128, wn = (w & 3) * 64;
    const int q = lane >> 4, l15 = lane & 15;
    const int srow = lane >> 2;                                // 16 rows / gload
    const int schunk = ((lane & 3) ^ ((lane >> 3) & 3)) * 16;  // pre-swizzled src chunk (bytes)

    float4v acc[8][4];
#pragma unroll
    for (int i = 0; i < 8; i++)
#pragma unroll
        for (int j = 0; j < 4; j++) acc[i][j] = (float4v){0.f, 0.f, 0.f, 0.f};

    // piece: 0 = A rows 0-127, 1 = A rows 128-255, 2 = B rows 0-127, 3 = B rows 128-255
    auto stage = [&](int T, int piece) {
        const int k0 = T * 64;
        unsigned char* buf = &smem[(T & 3) * 32768] + ((piece & 2) ? 16384 : 0);
        const int base = (piece & 2) ? bn : bm;
        const int rowoff = (piece & 1) * 128;
        gload_lds16(Xz + (size_t)(base + rowoff + w * 16 + srow) * 1024 + k0 + schunk,
                    buf + rowoff * 64 + w * 1024);
    };

    // prologue: 3 K-steps (12 gloads), land step 0
#pragma unroll
    for (int T = 0; T < 3; T++) {
        stage(T, 0); stage(T, 1); stage(T, 2); stage(T, 3);
    }
    asm volatile("s_waitcnt vmcnt(8)" ::: "memory");
    __builtin_amdgcn_s_barrier();

    long2v af[4], bfA[2], bfB[2];
    const int NT = 16;  // K=1024 / 64
    for (int t = 0; t < NT; ++t) {
        const unsigned char* bufA = &smem[(t & 3) * 32768];
        const unsigned char* bufB = bufA + 16384;

        // ---- ph1: mi 0-3 x ni 0-1 ----
#pragma unroll
        for (int mi = 0; mi < 4; mi++) {
            const int r = wm + mi * 16 + l15;
            af[mi] = *(const long2v*)(&bufA[r * 64 + ((q ^ ((r >> 1) & 3)) << 4)]);
        }
#pragma unroll
        for (int ni = 0; ni < 2; ni++) {
            const int r = wn + ni * 16 + l15;
            bfA[ni] = *(const long2v*)(&bufB[r * 64 + ((q ^ ((r >> 1) & 3)) << 4)]);
        }
        if (t + 3 < NT) stage(t + 3, 0);
        __builtin_amdgcn_s_barrier();
        __builtin_amdgcn_s_setprio(1);
#pragma unroll
        for (int s = 0; s < 2; s++)
#pragma unroll
            for (int mi = 0; mi < 4; mi++)
#pragma unroll
                for (int ni = 0; ni < 2; ni++)
                    acc[mi][ni] = __builtin_amdgcn_mfma_f32_16x16x32_fp8_fp8(
                        af[mi][s], bfA[ni][s], acc[mi][ni], 0, 0, 0);
        __builtin_amdgcn_s_setprio(0);
        __builtin_amdgcn_s_barrier();

        // ---- ph2: mi 0-3 x ni 2-3 ----
#pragma unroll
        for (int ni = 0; ni < 2; ni++) {
            const int r = wn + 32 + ni * 16 + l15;
            bfB[ni] = *(const long2v*)(&bufB[r * 64 + ((q ^ ((r >> 1) & 3)) << 4)]);
        }
        if (t + 3 < NT) stage(t + 3, 1);
        __builtin_amdgcn_s_barrier();
        __builtin_amdgcn_s_setprio(1);
#pragma unroll
        for (int s = 0; s < 2; s++)
#pragma unroll
            for (int mi = 0; mi < 4; mi++)
#pragma unroll
                for (int ni = 0; ni < 2; ni++)
                    acc[mi][2 + ni] = __builtin_amdgcn_mfma_f32_16x16x32_fp8_fp8(
                        af[mi][s], bfB[ni][s], acc[mi][2 + ni], 0, 0, 0);
        __builtin_amdgcn_s_setprio(0);
        __builtin_amdgcn_s_barrier();

        // ---- ph3: mi 4-7 x ni 2-3 ----
#pragma unroll
        for (int mi = 0; mi < 4; mi++) {
            const int r = wm + 64 + mi * 16 + l15;
            af[mi] = *(const long2v*)(&bufA[r * 64 + ((q ^ ((r >> 1) & 3)) << 4)]);
        }
        if (t + 3 < NT) stage(t + 3, 2);
        __builtin_amdgcn_s_barrier();
        __builtin_amdgcn_s_setprio(1);
#pragma unroll
        for (int s = 0; s < 2; s++)
#pragma unroll
            for (int mi = 0; mi < 4; mi++)
#pragma unroll
                for (int ni = 0; ni < 2; ni++)
                    acc[4 + mi][2 + ni] = __builtin_amdgcn_mfma_f32_16x16x32_fp8_fp8(
                        af[mi][s], bfB[ni][s], acc[4 + mi][2 + ni], 0, 0, 0);
        __builtin_amdgcn_s_setprio(0);
        __builtin_amdgcn_s_barrier();

        // ---- ph4: mi 4-7 x ni 0-1 (no new ds_reads) ----
        if (t + 3 < NT) stage(t + 3, 3);
        __builtin_amdgcn_s_barrier();
        __builtin_amdgcn_s_setprio(1);
#pragma unroll
        for (int s = 0; s < 2; s++)
#pragma unroll
            for (int mi = 0; mi < 4; mi++)
#pragma unroll
                for (int ni = 0; ni < 2; ni++)
                    acc[4 + mi][ni] = __builtin_amdgcn_mfma_f32_16x16x32_fp8_fp8(
                        af[mi][s], bfA[ni][s], acc[4 + mi][ni], 0, 0, 0);
        __builtin_amdgcn_s_setprio(0);
        if (t + 3 < NT)      asm volatile("s_waitcnt vmcnt(8)" ::: "memory");
        else if (t + 2 < NT) asm volatile("s_waitcnt vmcnt(4)" ::: "memory");
        else if (t + 1 < NT) asm volatile("s_waitcnt vmcnt(0)" ::: "memory");
        __builtin_amdgcn_s_barrier();
    }

    const float scale = 0.03125f;  // 1/sqrt(1024)
#pragma unroll
    for (int mi = 0; mi < 8; mi++) {
#pragma unroll
        for (int r = 0; r < 4; r++) {
            const int row = bm + wm + mi * 16 + q * 4 + r;
            const size_t ro = (size_t)row * 2048;
            float s = 0.f;
#pragma unroll
            for (int ni = 0; ni < 4; ni++) {
                const int col = bn + wn + ni * 16 + l15;
                const float m = mz[ro + col];
                float v = __expf(acc[mi][ni][r] * scale * m - 1e9f * (1.0f - m));
                s += v;
                Ez[ro + col] = f2b(v);
            }
            s += __shfl_xor(s, 8);
            s += __shfl_xor(s, 4);
            s += __shfl_xor(s, 2);
            s += __shfl_xor(s, 1);
            if (l15 == 0) atomicAdd(&rsz[row], s);
        }
    }
}

// fp32 [R][C] (batched z) -> outT bf16 [C][R]; optional outS bf16 + outQ fp8 [R][C].
__global__ __launch_bounds__(256)
void conv_trans(const float* __restrict__ in, ushort_t* __restrict__ outT,
                ushort_t* __restrict__ outS, unsigned char* __restrict__ outQ,
                int R, int C)
{
    __shared__ float tile[64][65];
    const int tx = threadIdx.x & 15, ty = threadIdx.x >> 4;
    const size_t zoff = (size_t)blockIdx.z * R * C;
    const int r0 = blockIdx.y * 64, c0 = blockIdx.x * 64;
#pragma unroll
    for (int j = 0; j < 4; j++) {
        const int r = ty + j * 16;
        const float4 v = *(const float4*)(in + zoff + (size_t)(r0 + r) * C + c0 + tx * 4);
        tile[r][tx * 4 + 0] = v.x;
        tile[r][tx * 4 + 1] = v.y;
        tile[r][tx * 4 + 2] = v.z;
        tile[r][tx * 4 + 3] = v.w;
        if (outS) {
            ushort4 o;
            o.x = f2b(v.x); o.y = f2b(v.y); o.z = f2b(v.z); o.w = f2b(v.w);
            *(ushort4*)(outS + zoff + (size_t)(r0 + r) * C + c0 + tx * 4) = o;
            uchar4 p;
            p.x = f2e4(v.x); p.y = f2e4(v.y); p.z = f2e4(v.z); p.w = f2e4(v.w);
            *(uchar4*)(outQ + zoff + (size_t)(r0 + r) * C + c0 + tx * 4) = p;
        }
    }
    __syncthreads();
    ushort_t* tp = outT + zoff;
#pragma unroll
    for (int j = 0; j < 4; j++) {
        const int cc = ty + j * 16;
        ushort4 o;
        o.x = f2b(tile[tx * 4 + 0][cc]);
        o.y = f2b(tile[tx * 4 + 1][cc]);
        o.z = f2b(tile[tx * 4 + 2][cc]);
        o.w = f2b(tile[tx * 4 + 3][cc]);
        *(ushort4*)(tp + (size_t)(c0 + cc) * R + r0 + tx * 4) = o;
    }
}

// LayerNorm over H=1024 (bf16 in, fp32 out), one block (256 thr) per row.
__global__ __launch_bounds__(256)
void ln_k(const ushort_t* __restrict__ Mt, const float* __restrict__ gamma,
          const float* __restrict__ beta, float* __restrict__ out)
{
    const size_t row = blockIdx.x;
    const int tid = threadIdx.x;
    const ushort4 u = *(const ushort4*)(Mt + row * 1024 + tid * 4);
    float x0 = b2f(u.x), x1 = b2f(u.y), x2 = b2f(u.z), x3 = b2f(u.w);
    float s  = x0 + x1 + x2 + x3;
    float s2 = x0 * x0 + x1 * x1 + x2 * x2 + x3 * x3;
#pragma unroll
    for (int off = 32; off > 0; off >>= 1) {
        s  += __shfl_down(s, off);
        s2 += __shfl_down(s2, off);
    }
    __shared__ float red[8];
    const int wave = tid >> 6, lane = tid & 63;
    if (lane == 0) { red[wave] = s; red[4 + wave] = s2; }
    __syncthreads();
    s  = red[0] + red[1] + red[2] + red[3];
    s2 = red[4] + red[5] + red[6] + red[7];
    const float mu  = s * (1.0f / 1024.0f);
    const float var = s2 * (1.0f / 1024.0f) - mu * mu;
    const float rinv = rsqrtf(var + 1e-12f);
    const float4 g = *(const float4*)(gamma + tid * 4);
    const float4 b = *(const float4*)(beta + tid * 4);
    float4 o;
    o.x = (x0 - mu) * rinv * g.x + b.x;
    o.y = (x1 - mu) * rinv * g.y + b.y;
    o.z = (x2 - mu) * rinv * g.z + b.z;
    o.w = (x3 - mu) * rinv * g.w + b.w;
    *(float4*)(out + row * 1024 + tid * 4) = o;
}

extern "C" void kernel_launch(void* const* d_in, const int* in_sizes, int n_in,
                              void* d_out, int out_size, void* d_ws, size_t ws_size,
                              hipStream_t stream)
{
    const float* X     = (const float*)d_in[0];  // [8,2048,1024]
    const float* masks = (const float*)d_in[1];  // [8,2048,2048]
    const float* Wm    = (const float*)d_in[2];  // [2048,1024]
    const float* bias  = (const float*)d_in[3];  // [1024]
    const float* gamma = (const float*)d_in[4];  // [1024]
    const float* beta  = (const float*)d_in[5];  // [1024]
    float* out = (float*)d_out;
    char* ws = (char*)d_ws;

    const int B = 8, S = 2048, H = 1024;

    // workspace layout (bytes): total 172,032,000
    ushort_t* Xb  = (ushort_t*)(ws);              // 33,554,432  X bf16 [B][S][H]
    ushort_t* XT  = (ushort_t*)(ws + 33554432);   // 33,554,432  X^T bf16 [B][H][S]
    ushort_t* WT  = (ushort_t*)(ws + 67108864);   //  4,194,304  W^T bf16 [H][2H]
    ushort_t* E   = (ushort_t*)(ws + 71303168);   // 67,108,864  exp(logits) bf16 [B][S][S]
    float*    rs  = (float*)   (ws + 138412032);  //     65,536  rowsums [B][S]
    ushort_t* CTX = (ushort_t*)(ws + 138477568);  // 33,554,432  context bf16 [B][S][H]
    unsigned char* X8 = (unsigned char*)CTX;      // alias: X8 dead before CTX written
    ushort_t* matching = E;                       // alias: E dead after GEMM2

    conv_trans<<<dim3(16, 32, 8), 256, 0, stream>>>(X, XT, Xb, X8, S, H);
    conv_trans<<<dim3(16, 32, 1), 256, 0, stream>>>(Wm, WT, nullptr, nullptr, 2 * H, H);
    hipMemsetAsync(rs, 0, (size_t)B * S * sizeof(float), stream);

    // GEMM1 (fp8, 4-phase): E = exp(mask(scale * X X^T)); rs += row sums
    gemm1_fp8<<<dim3(8, 8, 8), 512, 0, stream>>>(X8, masks, rs, E);

    // GEMM2 (bf16, 2-phase): CTX = (E . XT^T) / rowsum
    gemm_bt<2><<<dim3(8, 4, 8), 512, 0, stream>>>(
        E, E, 1 << 30, XT,
        S, H, S, S, S, H,
        (long)S * S, (long)H * S, (long)S * H,
        rs, nullptr, CTX);

    // GEMM3 (bf16, 2-phase): matching = [Xb|CTX] @ WT^T + bias -> bf16
    gemm_bt<3><<<dim3(64, 4, 1), 512, 0, stream>>>(
        Xb, CTX, H, WT,
        B * S, H, 2 * H, H, 2 * H, H,
        0, 0, 0,
        nullptr, bias, matching);

    ln_k<<<B * S, 256, 0, stream>>>(matching, gamma, beta, out);
}